// Round 5
// baseline (112.409 us; speedup 1.0000x reference)
//
#include <hip/hip_runtime.h>
#include <hip/hip_bf16.h>
#include <stdint.h>

// Problem constants
#define BB   32
#define CIN  128
#define HH   64
#define WW   64
#define COUT 256
#define OHH  62
#define OWW  62
#define PIX_PER_B (OHH*OWW)        // 3844
#define NPIX (BB*PIX_PER_B)        // 123008 = 961 * 128
#define KTOT (9*CIN)               // 1152
#define NKT  36                    // K-tiles of BK=32
#define SLOT 24576                 // A 16KB + X 8KB per K-tile

typedef __bf16 bf16x8 __attribute__((ext_vector_type(8)));
typedef float  f32x4  __attribute__((ext_vector_type(4)));
typedef uint16_t u16x8 __attribute__((ext_vector_type(8)));

__device__ __forceinline__ uint16_t f2bf(float f) {
    uint32_t u = __float_as_uint(f);
    uint32_t r = (u + 0x7FFFu + ((u >> 16) & 1u)) >> 16;
    return (uint16_t)r;
}

__device__ __forceinline__ void gload_lds16(const void* g, void* l) {
    __builtin_amdgcn_global_load_lds(
        (const __attribute__((address_space(1))) uint32_t*)g,
        (__attribute__((address_space(3))) uint32_t*)l, 16, 0, 0);
}

// -------- Prepass 1: NCHW fp32 -> NHWC bf16 ----------------------------------
__global__ void __launch_bounds__(256) to_nhwc(const float* __restrict__ in,
                                               uint16_t* __restrict__ out) {
    int slab = blockIdx.x;            // b*64 + h
    int b = slab >> 6, h = slab & 63;
    int w  = threadIdx.x & 63;
    int cp = threadIdx.x >> 6;        // 0..3
    const float* src = in + (((size_t)b * CIN) * HH + h) * WW + w;
    uint16_t* dst = out + ((size_t)slab * WW + w) * CIN;
    #pragma unroll
    for (int it = 0; it < 4; ++it) {
        int c0 = cp * 32 + it * 8;
        u16x8 v;
        #pragma unroll
        for (int j = 0; j < 8; ++j) v[j] = f2bf(src[(c0 + j) * (HH * WW)]);
        *reinterpret_cast<u16x8*>(dst + c0) = v;
    }
}

// -------- Prepass 2: OIHW fp32 -> bf16 [o][uv*128 + c] -----------------------
__global__ void __launch_bounds__(256) pack_w(const float* __restrict__ w,
                                              uint16_t* __restrict__ out) {
    int idx = blockIdx.x * 256 + threadIdx.x;     // < 256*1152
    int o = idx / KTOT;
    int k = idx - o * KTOT;
    int uv = k >> 7, c = k & 127;
    out[idx] = f2bf(w[(o * CIN + c) * 9 + uv]);
}

// -------- Main: 256x128 tile, 8 waves (4Mx2N, 64x64 each), BK=32 -------------
// Lean phase: {stage(t+2) -> slot(t-1); 8 ds_read_b128; 16 MFMA; vmcnt(3);
// ONE s_barrier}. No setprio, no forced lgkm drain, no sched_barrier — the
// compiler interleaves reads/MFMA with fine lgkmcnt (m97 evidence); every
// ds_read is consumed by MFMA pre-barrier, so slot(t-1) reads are complete
// before anyone (post-B(t-1)) issues writes into it -> WAR-safe with a single
// barrier. Ring-3 slots (73KB) -> 2 blocks/CU; counted vmcnt(3) keeps one
// K-tile of loads in flight, never drained to 0 until the tail.
__global__ void __launch_bounds__(512, 4) conv_k32(
        const uint16_t* __restrict__ Xg,   // NHWC bf16 [32][64][64][128]
        const uint16_t* __restrict__ Wg,   // bf16 [256][1152], k=(uv,c)
        const float*    __restrict__ bias, // [256]
        float*          __restrict__ out)  // NCHW fp32 [32][256][62][62]
{
    __shared__ char lds[3 * SLOT + 1024];
    int* pbase = (int*)(lds + 3 * SLOT);   // [128] NHWC elem off of pixel
    int* obase = pbase + 128;              // [128] out flat base (o=0)

    const int tid  = threadIdx.x;
    const int lane = tid & 63;
    const int wid  = tid >> 6;             // 0..7

    // bijective XCD swizzle: nwg=961, q=120, r=1
    int bid = blockIdx.x;
    int xcd = bid & 7, lid = bid >> 3;
    int nt  = (xcd == 0 ? lid : 121 + (xcd - 1) * 120 + lid);

    if (tid < 128) {
        int n   = nt * 128 + tid;
        int b   = n / PIX_PER_B;
        int rem = n - b * PIX_PER_B;
        int oh  = rem / OWW;
        int ow  = rem - oh * OWW;
        pbase[tid] = ((b * 64 + oh) * 64 + ow) * 128;
        obase[tid] = b * (COUT * PIX_PER_B) + rem;
    }
    __syncthreads();

    // ---- staging geometry ----
    // A load l: row = l*128 + (tid>>2); X: row = tid>>2. stored chunk = tid&3,
    // logical chunk = (tid&3) ^ ((row>>1)&3) = (tid&3) ^ ((tid>>3)&3).
    const int cs   = (((tid & 3) ^ ((tid >> 3) & 3)) << 4);
    const int ldst = tid * 16;
    // fold swizzled chunk + row base into 64-bit pointers once
    const char* aptr0 = (const char*)Wg + (tid >> 2) * (KTOT * 2) + cs;
    const char* aptr1 = (const char*)Wg + (128 + (tid >> 2)) * (KTOT * 2) + cs;
    const char* xptr  = (const char*)Xg + pbase[tid >> 2] * 2 + cs;

    // ---- fragment ds_read byte offsets ----
    const int wm = wid >> 1, wn = wid & 1;   // 4 M-waves x 2 N-waves
    int aro[4], xro[4];
    #pragma unroll
    for (int mi = 0; mi < 4; ++mi) {
        int row = wm * 64 + mi * 16 + (lane & 15);
        aro[mi] = row * 64 + ((((lane >> 4) ^ ((row >> 1) & 3))) << 4);
    }
    #pragma unroll
    for (int nj = 0; nj < 4; ++nj) {
        int row = wn * 64 + nj * 16 + (lane & 15);
        xro[nj] = 16384 + row * 64 + ((((lane >> 4) ^ ((row >> 1) & 3))) << 4);
    }

    f32x4 acc[4][4] = {};

    // uniform k-offsets: Wg is linear in t (t*64 B); X needs (u,v) decode:
    // xoff(t) = (u<<14) | (v<<8) | ((t&3)<<6)   (disjoint bit ranges)
    auto stage = [&](int t, char* dst) {
        int uvv = t >> 2;
        int u   = (uvv * 11) >> 5;             // uvv/3 for uvv<9
        int v   = uvv - u * 3;
        int xo  = (u << 14) | (v << 8) | ((t & 3) << 6);
        gload_lds16(aptr0 + t * 64, dst + ldst);
        gload_lds16(aptr1 + t * 64, dst + 8192 + ldst);
        gload_lds16(xptr + xo, dst + 16384 + ldst);
    };

// Lean phase. S/S2 are compile-time slot ids; STG: stage t+2; VMC: 0 none,
// 1 vmcnt(3), 2 vmcnt(0); BAR: trailing barrier.
#define PHASE(T, S, S2, STG, VMC, BAR) do {                                    \
    char* _slot = lds + (S) * SLOT;                                            \
    if (STG) stage((T) + 2, lds + (S2) * SLOT);                                \
    bf16x8 af[4], xf[4];                                                       \
    _Pragma("unroll") for (int mi = 0; mi < 4; ++mi)                           \
        af[mi] = *reinterpret_cast<const bf16x8*>(_slot + aro[mi]);            \
    _Pragma("unroll") for (int nj = 0; nj < 4; ++nj)                           \
        xf[nj] = *reinterpret_cast<const bf16x8*>(_slot + xro[nj]);            \
    _Pragma("unroll") for (int mi = 0; mi < 4; ++mi)                           \
      _Pragma("unroll") for (int nj = 0; nj < 4; ++nj)                         \
        acc[mi][nj] = __builtin_amdgcn_mfma_f32_16x16x32_bf16(                 \
            af[mi], xf[nj], acc[mi][nj], 0, 0, 0);                             \
    if ((VMC) == 1) asm volatile("s_waitcnt vmcnt(3)" ::: "memory");           \
    else if ((VMC) == 2) asm volatile("s_waitcnt vmcnt(0)" ::: "memory");      \
    if (BAR) __builtin_amdgcn_s_barrier();                                     \
} while (0)

    // ---- prologue: stage K-tiles 0,1 ----
    stage(0, lds);
    stage(1, lds + SLOT);
    asm volatile("s_waitcnt vmcnt(3)" ::: "memory");   // tile 0 resident
    __builtin_amdgcn_s_barrier();

    // ---- main: 11 x 3 phases (t=0..32), then peeled tail t=33,34,35 ----
    for (int i = 0; i < 11; ++i) {
        const int t = 3 * i;
        PHASE(t + 0, 0, 2, 1, 1, 1);
        PHASE(t + 1, 1, 0, 1, 1, 1);
        PHASE(t + 2, 2, 1, 1, 1, 1);
    }
    PHASE(33, 0, 2, 1, 1, 1);     // stage(35) -> slot 2
    PHASE(34, 1, 0, 0, 2, 1);     // drain all
    PHASE(35, 2, 1, 0, 0, 0);
#undef PHASE

    // ---- epilogue: C/D col=lane&15 (pixel), row=(lane>>4)*4+reg (o) ----
    #pragma unroll
    for (int mi = 0; mi < 4; ++mi) {
        int o = wm * 64 + mi * 16 + ((lane >> 4) << 2);
        #pragma unroll
        for (int reg = 0; reg < 4; ++reg) {
            float bv = bias[o + reg];
            #pragma unroll
            for (int nj = 0; nj < 4; ++nj) {
                int pl = wn * 64 + nj * 16 + (lane & 15);
                out[obase[pl] + (o + reg) * PIX_PER_B] = acc[mi][nj][reg] + bv;
            }
        }
    }
}

// -------- Fallback (ws too small): naive direct conv -------------------------
__global__ void __launch_bounds__(256) conv_naive(const float* __restrict__ in,
                                                  const float* __restrict__ w,
                                                  const float* __restrict__ bias,
                                                  float* __restrict__ out) {
    long idx = (long)blockIdx.x * 256 + threadIdx.x;
    int t = (int)idx;
    int ow = t % OWW; t /= OWW;
    int oh = t % OHH; t /= OHH;
    int o  = t % COUT;
    int b  = t / COUT;
    float s = bias[o];
    for (int c = 0; c < CIN; ++c)
        for (int u = 0; u < 3; ++u)
            for (int v = 0; v < 3; ++v)
                s += in[((b * CIN + c) * HH + oh + u) * WW + ow + v] *
                     w[((o * CIN + c) * 3 + u) * 3 + v];
    out[idx] = s;
}

extern "C" void kernel_launch(void* const* d_in, const int* in_sizes, int n_in,
                              void* d_out, int out_size, void* d_ws, size_t ws_size,
                              hipStream_t stream) {
    const float* in   = (const float*)d_in[0];
    const float* wt   = (const float*)d_in[1];
    const float* bias = (const float*)d_in[2];
    float* out = (float*)d_out;

    const size_t xg_elems = (size_t)BB * HH * WW * CIN;       // 33.5M bf16
    const size_t wg_elems = (size_t)COUT * KTOT;              // 295K bf16
    const size_t need = (xg_elems + wg_elems) * sizeof(uint16_t);

    if (ws_size < need) {
        long total = (long)BB * COUT * OHH * OWW;
        conv_naive<<<(int)((total + 255) / 256), 256, 0, stream>>>(in, wt, bias, out);
        return;
    }

    uint16_t* Xg = (uint16_t*)d_ws;
    uint16_t* Wg = Xg + xg_elems;

    to_nhwc<<<BB * HH, 256, 0, stream>>>(in, Xg);
    pack_w<<<(COUT * KTOT) / 256, 256, 0, stream>>>(wt, Wg);
    conv_k32<<<NPIX / 128, 512, 0, stream>>>(Xg, Wg, bias, out);
}

// Round 6
// 105.868 us; speedup vs baseline: 1.0618x; 1.0618x over previous
//
#include <hip/hip_runtime.h>
#include <hip/hip_bf16.h>
#include <stdint.h>

// Problem constants
#define BB   32
#define CIN  128
#define HH   64
#define WW   64
#define COUT 256
#define OHH  62
#define OWW  62
#define PIX_PER_B (OHH*OWW)        // 3844
#define NPIX (BB*PIX_PER_B)        // 123008 = 961 * 128
#define KTOT (9*CIN)               // 1152
#define NKT  36                    // K-tiles of BK=32
#define SLOT 24576                 // A 16KB + X 8KB per K-tile

typedef __bf16 bf16x8 __attribute__((ext_vector_type(8)));
typedef float  f32x4  __attribute__((ext_vector_type(4)));
typedef uint16_t u16x8 __attribute__((ext_vector_type(8)));

__device__ __forceinline__ uint16_t f2bf(float f) {
    uint32_t u = __float_as_uint(f);
    uint32_t r = (u + 0x7FFFu + ((u >> 16) & 1u)) >> 16;
    return (uint16_t)r;
}

__device__ __forceinline__ void gload_lds16(const void* g, void* l) {
    __builtin_amdgcn_global_load_lds(
        (const __attribute__((address_space(1))) uint32_t*)g,
        (__attribute__((address_space(3))) uint32_t*)l, 16, 0, 0);
}

// -------- Prepass 1: NCHW fp32 -> NHWC bf16 ----------------------------------
__global__ void __launch_bounds__(256) to_nhwc(const float* __restrict__ in,
                                               uint16_t* __restrict__ out) {
    int slab = blockIdx.x;            // b*64 + h
    int b = slab >> 6, h = slab & 63;
    int w  = threadIdx.x & 63;
    int cp = threadIdx.x >> 6;        // 0..3
    const float* src = in + (((size_t)b * CIN) * HH + h) * WW + w;
    uint16_t* dst = out + ((size_t)slab * WW + w) * CIN;
    #pragma unroll
    for (int it = 0; it < 4; ++it) {
        int c0 = cp * 32 + it * 8;
        u16x8 v;
        #pragma unroll
        for (int j = 0; j < 8; ++j) v[j] = f2bf(src[(c0 + j) * (HH * WW)]);
        *reinterpret_cast<u16x8*>(dst + c0) = v;
    }
}

// -------- Prepass 2: OIHW fp32 -> bf16 [o][uv*128 + c] -----------------------
__global__ void __launch_bounds__(256) pack_w(const float* __restrict__ w,
                                              uint16_t* __restrict__ out) {
    int idx = blockIdx.x * 256 + threadIdx.x;     // < 256*1152
    int o = idx / KTOT;
    int k = idx - o * KTOT;
    int uv = k >> 7, c = k & 127;
    out[idx] = f2bf(w[(o * CIN + c) * 9 + uv]);
}

// -------- Main: 256x128 tile, 4 waves (2Mx2N, 128x64 each), BK=32 ------------
// Phase: {stage(t+2)->slot(t-1) [6 gload_lds]; 12 ds_read_b128 (xf4+af8);
// setprio(1); 32 MFMA; setprio(0); vmcnt(6); ONE barrier}. 128x64 wave tiles
// cut LDS reads to 375 B/MFMA (vs 512 at 64x64); compiler's native lgkmcnt
// ladder overlaps MFMA groups with remaining reads. Ring-3 slots (73KB) ->
// 2 blocks/CU; counted vmcnt(6) keeps one K-tile of loads in flight.
__global__ void __launch_bounds__(256, 2) conv_k32(
        const uint16_t* __restrict__ Xg,   // NHWC bf16 [32][64][64][128]
        const uint16_t* __restrict__ Wg,   // bf16 [256][1152], k=(uv,c)
        const float*    __restrict__ bias, // [256]
        float*          __restrict__ out)  // NCHW fp32 [32][256][62][62]
{
    __shared__ char lds[3 * SLOT + 1024];
    int* pbase = (int*)(lds + 3 * SLOT);   // [128] NHWC elem off of pixel
    int* obase = pbase + 128;              // [128] out flat base (o=0)

    const int tid  = threadIdx.x;
    const int lane = tid & 63;
    const int wid  = tid >> 6;             // 0..3

    // bijective XCD swizzle: nwg=961, q=120, r=1
    int bid = blockIdx.x;
    int xcd = bid & 7, lid = bid >> 3;
    int nt  = (xcd == 0 ? lid : 121 + (xcd - 1) * 120 + lid);

    if (tid < 128) {
        int n   = nt * 128 + tid;
        int b   = n / PIX_PER_B;
        int rem = n - b * PIX_PER_B;
        int oh  = rem / OWW;
        int ow  = rem - oh * OWW;
        pbase[tid] = ((b * 64 + oh) * 64 + ow) * 128;
        obase[tid] = b * (COUT * PIX_PER_B) + rem;
    }
    __syncthreads();

    // ---- staging geometry ----
    // Instr I covers A rows I*64+(tid>>2) (I=0..3) / X pixels J*64+(tid>>2);
    // stored chunk = tid&3, logical chunk = (tid&3)^((row>>1)&3)
    //              = (tid&3)^((tid>>3)&3) since row = tid>>2.
    const int cs   = (((tid & 3) ^ ((tid >> 3) & 3)) << 4);
    const int ldst = tid * 16;
    const char* aptr0 = (const char*)Wg + ((tid >> 2) + 0)   * (KTOT * 2) + cs;
    const char* aptr1 = (const char*)Wg + ((tid >> 2) + 64)  * (KTOT * 2) + cs;
    const char* aptr2 = (const char*)Wg + ((tid >> 2) + 128) * (KTOT * 2) + cs;
    const char* aptr3 = (const char*)Wg + ((tid >> 2) + 192) * (KTOT * 2) + cs;
    const char* xptr0 = (const char*)Xg + pbase[(tid >> 2)] * 2 + cs;
    const char* xptr1 = (const char*)Xg + pbase[(tid >> 2) + 64] * 2 + cs;

    // ---- fragment ds_read byte offsets ----
    const int wm = wid >> 1, wn = wid & 1;   // 2 M-waves x 2 N-waves
    int aro[8], xro[4];
    #pragma unroll
    for (int mi = 0; mi < 8; ++mi) {
        int row = wm * 128 + mi * 16 + (lane & 15);
        aro[mi] = row * 64 + ((((lane >> 4) ^ ((row >> 1) & 3))) << 4);
    }
    #pragma unroll
    for (int nj = 0; nj < 4; ++nj) {
        int row = wn * 64 + nj * 16 + (lane & 15);
        xro[nj] = 16384 + row * 64 + ((((lane >> 4) ^ ((row >> 1) & 3))) << 4);
    }

    f32x4 acc[8][4] = {};

    // uniform k-offsets: Wg linear in t (t*64 B); X: (u<<14)|(v<<8)|((t&3)<<6)
    auto stage = [&](int t, char* dst) {
        int uvv = t >> 2;
        int u   = (uvv * 11) >> 5;             // uvv/3 for uvv<9
        int v   = uvv - u * 3;
        int xo  = (u << 14) | (v << 8) | ((t & 3) << 6);
        gload_lds16(aptr0 + t * 64, dst + ldst);
        gload_lds16(aptr1 + t * 64, dst + 4096 + ldst);
        gload_lds16(aptr2 + t * 64, dst + 8192 + ldst);
        gload_lds16(aptr3 + t * 64, dst + 12288 + ldst);
        gload_lds16(xptr0 + xo, dst + 16384 + ldst);
        gload_lds16(xptr1 + xo, dst + 20480 + ldst);
    };

// S/S2 compile-time slot ids; STG: stage t+2; VMC: 0 none, 1 vmcnt(6),
// 2 vmcnt(0); BAR: trailing barrier.
#define PHASE(T, S, S2, STG, VMC, BAR) do {                                    \
    char* _slot = lds + (S) * SLOT;                                            \
    if (STG) stage((T) + 2, lds + (S2) * SLOT);                                \
    bf16x8 af[8], xf[4];                                                       \
    _Pragma("unroll") for (int nj = 0; nj < 4; ++nj)                           \
        xf[nj] = *reinterpret_cast<const bf16x8*>(_slot + xro[nj]);            \
    _Pragma("unroll") for (int mi = 0; mi < 8; ++mi)                           \
        af[mi] = *reinterpret_cast<const bf16x8*>(_slot + aro[mi]);            \
    __builtin_amdgcn_s_setprio(1);                                             \
    _Pragma("unroll") for (int mi = 0; mi < 8; ++mi)                           \
      _Pragma("unroll") for (int nj = 0; nj < 4; ++nj)                         \
        acc[mi][nj] = __builtin_amdgcn_mfma_f32_16x16x32_bf16(                 \
            af[mi], xf[nj], acc[mi][nj], 0, 0, 0);                             \
    __builtin_amdgcn_s_setprio(0);                                             \
    if ((VMC) == 1) asm volatile("s_waitcnt vmcnt(6)" ::: "memory");           \
    else if ((VMC) == 2) asm volatile("s_waitcnt vmcnt(0)" ::: "memory");      \
    if (BAR) __builtin_amdgcn_s_barrier();                                     \
} while (0)

    // ---- prologue: stage K-tiles 0,1 ----
    stage(0, lds);
    stage(1, lds + SLOT);
    asm volatile("s_waitcnt vmcnt(6)" ::: "memory");   // tile 0 resident
    __builtin_amdgcn_s_barrier();

    // ---- main: 11 x 3 phases (t=0..32), then peeled tail t=33,34,35 ----
    for (int i = 0; i < 11; ++i) {
        PHASE(3 * i + 0, 0, 2, 1, 1, 1);
        PHASE(3 * i + 1, 1, 0, 1, 1, 1);
        PHASE(3 * i + 2, 2, 1, 1, 1, 1);
    }
    PHASE(33, 0, 2, 1, 1, 1);     // stage(35) -> slot 2
    PHASE(34, 1, 0, 0, 2, 1);     // drain all
    PHASE(35, 2, 1, 0, 0, 0);
#undef PHASE

    // ---- epilogue: C/D col=lane&15 (pixel), row=(lane>>4)*4+reg (o) ----
    #pragma unroll
    for (int mi = 0; mi < 8; ++mi) {
        int o = wm * 128 + mi * 16 + ((lane >> 4) << 2);
        #pragma unroll
        for (int reg = 0; reg < 4; ++reg) {
            float bv = bias[o + reg];
            #pragma unroll
            for (int nj = 0; nj < 4; ++nj) {
                int pl = wn * 64 + nj * 16 + (lane & 15);
                out[obase[pl] + (o + reg) * PIX_PER_B] = acc[mi][nj][reg] + bv;
            }
        }
    }
}

// -------- Fallback (ws too small): naive direct conv -------------------------
__global__ void __launch_bounds__(256) conv_naive(const float* __restrict__ in,
                                                  const float* __restrict__ w,
                                                  const float* __restrict__ bias,
                                                  float* __restrict__ out) {
    long idx = (long)blockIdx.x * 256 + threadIdx.x;
    int t = (int)idx;
    int ow = t % OWW; t /= OWW;
    int oh = t % OHH; t /= OHH;
    int o  = t % COUT;
    int b  = t / COUT;
    float s = bias[o];
    for (int c = 0; c < CIN; ++c)
        for (int u = 0; u < 3; ++u)
            for (int v = 0; v < 3; ++v)
                s += in[((b * CIN + c) * HH + oh + u) * WW + ow + v] *
                     w[((o * CIN + c) * 3 + u) * 3 + v];
    out[idx] = s;
}

extern "C" void kernel_launch(void* const* d_in, const int* in_sizes, int n_in,
                              void* d_out, int out_size, void* d_ws, size_t ws_size,
                              hipStream_t stream) {
    const float* in   = (const float*)d_in[0];
    const float* wt   = (const float*)d_in[1];
    const float* bias = (const float*)d_in[2];
    float* out = (float*)d_out;

    const size_t xg_elems = (size_t)BB * HH * WW * CIN;       // 33.5M bf16
    const size_t wg_elems = (size_t)COUT * KTOT;              // 295K bf16
    const size_t need = (xg_elems + wg_elems) * sizeof(uint16_t);

    if (ws_size < need) {
        long total = (long)BB * COUT * OHH * OWW;
        conv_naive<<<(int)((total + 255) / 256), 256, 0, stream>>>(in, wt, bias, out);
        return;
    }

    uint16_t* Xg = (uint16_t*)d_ws;
    uint16_t* Wg = Xg + xg_elems;

    to_nhwc<<<BB * HH, 256, 0, stream>>>(in, Xg);
    pack_w<<<(COUT * KTOT) / 256, 256, 0, stream>>>(wt, Wg);
    conv_k32<<<NPIX / 128, 256, 0, stream>>>(Xg, Wg, bias, out);
}